// Round 6
// baseline (19897.739 us; speedup 1.0000x reference)
//
#include <hip/hip_runtime.h>
#include <math.h>

#define NWG 256
#define NTHR 512
static constexpr int S = 512, B = 64, I = 128, H = 512;

// ws layout (float units)
static constexpr size_t OFF_BUF0   = 0;                                  // S*B*H: x_proj -> out_pre in place
static constexpr size_t OFF_PCTX   = (size_t)S * B * H;                  // [64][4][520] pctx blocks (P2 h-exch unions here)
static constexpr size_t OFF_H3X    = OFF_PCTX + (size_t)64 * 4 * 520;    // [64][512] P3 h quarters
static constexpr size_t OFF_ACTR   = OFF_H3X + (size_t)64 * 512;         // [64][4][16] u32 pctx counters
static constexpr size_t OFF_HCTR   = OFF_ACTR + (size_t)64 * 4 * 16;     // [64][4][16] u32 h counters
static constexpr size_t OFF_GFLAGS = OFF_HCTR + (size_t)64 * 4 * 16;     // [256][16] u32 global barrier flags
static constexpr size_t OFF_END    = OFF_GFLAGS + (size_t)256 * 16;

typedef float f32x2 __attribute__((ext_vector_type(2)));
typedef float f32x4 __attribute__((ext_vector_type(4)));
#define PIN4(x) asm volatile("" : "+v"(x))

// ---- coherent (sc0 sc1: L1+L2 bypass, served at L3 coherence point) ops ----
__device__ __forceinline__ void st_g1(float* p, float v) {
  asm volatile("global_store_dword %0, %1, off sc0 sc1" :: "v"(p), "v"(v) : "memory");
}
__device__ __forceinline__ void st_g2(float* p, f32x2 v) {
  asm volatile("global_store_dwordx2 %0, %1, off sc0 sc1" :: "v"(p), "v"(v) : "memory");
}
__device__ __forceinline__ void st_gu(unsigned* p, unsigned v) {
  asm volatile("global_store_dword %0, %1, off sc0 sc1" :: "v"(p), "v"(v) : "memory");
}
__device__ __forceinline__ f32x4 ld_g4(const float* p) {
  f32x4 v;
  asm volatile("global_load_dwordx4 %0, %1, off sc0 sc1\n\ts_waitcnt vmcnt(0)"
               : "=&v"(v) : "v"(p) : "memory");
  return v;
}
__device__ __forceinline__ void ld_3c(const float* v0, const float* v1, const float* v2,
                                      const float* m0, const float* m1, const float* m2,
                                      float& a, float& b, float& c,
                                      f32x2& x, f32x2& y, f32x2& z) {
  asm volatile("global_load_dword %0, %6, off sc0 sc1\n\t"
               "global_load_dword %1, %7, off sc0 sc1\n\t"
               "global_load_dword %2, %8, off sc0 sc1\n\t"
               "global_load_dwordx2 %3, %9, off sc0 sc1\n\t"
               "global_load_dwordx2 %4, %10, off sc0 sc1\n\t"
               "global_load_dwordx2 %5, %11, off sc0 sc1\n\t"
               "s_waitcnt vmcnt(0)"
               : "=&v"(a), "=&v"(b), "=&v"(c), "=&v"(x), "=&v"(y), "=&v"(z)
               : "v"(v0), "v"(v1), "v"(v2), "v"(m0), "v"(m1), "v"(m2) : "memory");
}
__device__ __forceinline__ void poll3_ge(const unsigned* p0, const unsigned* p1,
                                         const unsigned* p2, unsigned tgt) {
  unsigned a, b, c;
  do {
    asm volatile("global_load_dword %0, %3, off sc0 sc1\n\t"
                 "global_load_dword %1, %4, off sc0 sc1\n\t"
                 "global_load_dword %2, %5, off sc0 sc1\n\t"
                 "s_waitcnt vmcnt(0)"
                 : "=&v"(a), "=&v"(b), "=&v"(c)
                 : "v"(p0), "v"(p1), "v"(p2) : "memory");
  } while (a < tgt || b < tgt || c < tgt);
}
__device__ __forceinline__ void vm_drain() { asm volatile("s_waitcnt vmcnt(0)" ::: "memory"); }

__device__ __forceinline__ void gbar_all(unsigned* gflags, int wg, unsigned gen) {
  __syncthreads();
  if (threadIdx.x == 0)
    __hip_atomic_store(gflags + (size_t)wg * 16, gen, __ATOMIC_RELEASE, __HIP_MEMORY_SCOPE_AGENT);
  if (threadIdx.x < 256) {
    while (__hip_atomic_load(gflags + (size_t)threadIdx.x * 16, __ATOMIC_ACQUIRE,
                             __HIP_MEMORY_SCOPE_AGENT) < gen) {}
  }
  __syncthreads();
}

// LDS arena (floats): wih_tail [128][204] | merge 8x512 | ml 16 | hA 512 | hB 512 | ctx2 512 | flags 16
static constexpr int L_TAIL = 0;          // 26112
static constexpr int L_MRG  = 26112;      // 4096
static constexpr int L_ML   = 30208;      // 16
static constexpr int L_HA   = 30224;      // 512
static constexpr int L_HB   = 30736;      // 512
static constexpr int L_CTX  = 31248;      // 512
static constexpr int L_FLG  = 31760;      // 16
// total 31776 floats = 127,104 B  (< 128 KiB, proven feasible on gfx950)

__global__ __launch_bounds__(NTHR, 1) void attn_fused(
    const float* __restrict__ inputs,
    const float* __restrict__ Wih_pre, const float* __restrict__ Whh_pre,
    const float* __restrict__ bih_pre, const float* __restrict__ bhh_pre,
    const float* __restrict__ Wih_post, const float* __restrict__ Whh_post,
    const float* __restrict__ bih_post, const float* __restrict__ bhh_post,
    const float* __restrict__ Wfc, const float* __restrict__ bfc,
    float* __restrict__ out, float* __restrict__ ws)
{
  float* buf0  = ws + OFF_BUF0;
  float* pctxg = ws + OFF_PCTX;
  float* h3xg  = ws + OFF_H3X;
  unsigned* actrg  = (unsigned*)(ws + OFF_ACTR);
  unsigned* hctrg  = (unsigned*)(ws + OFF_HCTR);
  unsigned* gflags = (unsigned*)(ws + OFF_GFLAGS);

  const int wg   = blockIdx.x;
  const int tid  = threadIdx.x;
  const int lane = tid & 63;
  const int wv   = tid >> 6;
  const int b    = wg & 63;
  const int part = wg >> 6;
  const int q1 = (part + 1) & 3, q2 = (part + 2) & 3, q3 = (part + 3) & 3;

  unsigned* hc_own = hctrg + ((size_t)b * 4 + part) * 16;
  unsigned* hc1 = hctrg + ((size_t)b * 4 + q1) * 16;
  unsigned* hc2 = hctrg + ((size_t)b * 4 + q2) * 16;
  unsigned* hc3 = hctrg + ((size_t)b * 4 + q3) * 16;
  unsigned* ac_own = actrg + ((size_t)b * 4 + part) * 16;
  unsigned* ac1 = actrg + ((size_t)b * 4 + q1) * 16;
  unsigned* ac2 = actrg + ((size_t)b * 4 + q2) * 16;
  unsigned* ac3 = actrg + ((size_t)b * 4 + q3) * 16;

  __shared__ __align__(16) float smem[31776];

  // ================= P1: x_proj = inputs @ W_ih_pre^T + (b_ih+b_hh) ==========
  {
    const int h = tid;
    f32x4 Wr[32];
    const f32x4* wrow = (const f32x4*)(Wih_pre + (size_t)h * I);
    #pragma unroll
    for (int c = 0; c < 32; ++c) Wr[c] = wrow[c];
    const float bias = bih_pre[h] + bhh_pre[h];
    const int r0 = wg * 128;
    for (int t2 = 0; t2 < 2; ++t2) {
      __syncthreads();
      const f32x4* src = (const f32x4*)(inputs + (size_t)(r0 + t2 * 64) * I);
      for (int idx = tid; idx < 64 * I / 4; idx += NTHR)
        ((f32x4*)smem)[idx] = src[idx];
      __syncthreads();
      for (int r = 0; r < 64; ++r) {
        const f32x4* arow = (const f32x4*)(smem + r * I);
        float acc0 = 0.f, acc1 = 0.f;
        #pragma unroll
        for (int c = 0; c < 32; c += 2) {
          f32x4 a0 = arow[c], a1 = arow[c + 1];
          acc0 += a0.x * Wr[c].x + a0.y * Wr[c].y + a0.z * Wr[c].z + a0.w * Wr[c].w;
          acc1 += a1.x * Wr[c+1].x + a1.y * Wr[c+1].y + a1.z * Wr[c+1].z + a1.w * Wr[c+1].w;
        }
        buf0[(size_t)(r0 + t2 * 64 + r) * H + h] = acc0 + acc1 + bias;
      }
    }
  }
  gbar_all(gflags, wg, 1u);

  // ================= P2: pre-RNN, 512 steps, per-batch (4 WGs) ==============
  const int j  = part * 128 + (tid >> 2);
  const int kq = tid & 3;
  {
    f32x4 wpre[32];
    const f32x4* wrow = (const f32x4*)(Whh_pre + (size_t)j * H);
    #pragma unroll
    for (int i = 0; i < 32; ++i) { wpre[i] = wrow[4 * i + kq]; PIN4(wpre[i]); }

    float* hst = smem + L_HA;
    hst[tid] = 0.f;
    __syncthreads();

    for (int t = 0; t < S; ++t) {
      float* brow = buf0 + ((size_t)t * B + b) * H;
      float xp = brow[j];
      const f32x4* hst4 = (const f32x4*)hst;
      float d = 0.f;
      #pragma unroll
      for (int i = 0; i < 32; ++i) {
        f32x4 hv = hst4[4 * i + kq];
        d += wpre[i].x * hv.x + wpre[i].y * hv.y + wpre[i].z * hv.z + wpre[i].w * hv.w;
      }
      d += __shfl_xor(d, 1);
      d += __shfl_xor(d, 2);
      float hnew = tanhf(xp + d);
      const int par = (t + 1) & 1;
      float* slot = pctxg + (((size_t)b * 2 + par) * 4 + part) * 128;
      if (kq == 0) {
        brow[j] = hnew;
        st_g1(slot + (tid >> 2), hnew);
      }
      vm_drain();
      __syncthreads();
      if (tid == 0) st_gu(hc_own, (unsigned)(t + 1));
      if (wv == 0) poll3_ge(hc1, hc2, hc3, (unsigned)(t + 1));
      __syncthreads();
      if (tid < 128) {
        f32x4 hv = ld_g4(pctxg + (((size_t)b * 2 + par) * 4) * 128 + (size_t)tid * 4);
        ((f32x4*)hst)[tid] = hv;
      }
      __syncthreads();
    }
  }
  gbar_all(gflags, wg, 2u);

  // ---- G strip register-resident (normal loads; asm stores block remat) ----
  f32x4 ga[16], gb[16];
  {
    const int s0 = part * 128 + wv * 16;
    #pragma unroll
    for (int i = 0; i < 16; ++i) {
      const float* row = buf0 + ((size_t)(s0 + i) * B + b) * H;
      ga[i] = *(const f32x4*)(row + lane * 4);
      gb[i] = *(const f32x4*)(row + 256 + lane * 4);
    }
  }

  // ---- wih: head k<320 in regs (pinned), tail k in [320,512) in LDS --------
  f32x4 wihh[20];
  {
    const f32x4* wr1 = (const f32x4*)(Wih_post + (size_t)j * H);
    #pragma unroll
    for (int i = 0; i < 20; ++i) { wihh[i] = wr1[4 * i + kq]; PIN4(wihh[i]); }
    // stage tail: [128 rows][192 floats] -> [row][204] (16B-aligned, padded)
    for (int idx = tid; idx < 128 * 48; idx += NTHR) {
      int row = idx / 48, f4c = idx % 48;
      f32x4 v = ((const f32x4*)(Wih_post + (size_t)(part * 128 + row) * H + 320))[f4c];
      *(f32x4*)(smem + L_TAIL + row * 204 + f4c * 4) = v;
    }
  }
  const f32x4* whr = (const f32x4*)(Whh_post + (size_t)j * H);
  const float bp3 = bih_post[j] + bhh_post[j];

  float* blk_own = pctxg + ((size_t)b * 4 + part) * 520;
  float* blk1 = pctxg + ((size_t)b * 4 + q1) * 520;
  float* blk2 = pctxg + ((size_t)b * 4 + q2) * 520;
  float* blk3 = pctxg + ((size_t)b * 4 + q3) * 520;

  float* hcur = smem + L_HA;
  float* hoth = smem + L_HB;
  hcur[tid] = 0.f;
  __syncthreads();

  // ================= P3: attention loop, <=512 steps, per-batch ==============
  for (int u = 0; u < H; ++u) {
    // z2 = Whh_post(j-row, streamed from L2) . h_old -- issued early, used in 3c
    float zacc = 0.f;
    {
      const f32x4* h4 = (const f32x4*)hcur;
      #pragma unroll
      for (int i = 0; i < 32; ++i) {
        f32x4 w = whr[4 * i + kq];
        f32x4 hv = h4[4 * i + kq];
        zacc += w.x * hv.x + w.y * hv.y + w.z * hv.z + w.w * hv.w;
      }
    }

    // ---- 3a: scores + softmax partials + ctx partial (registers) ----
    float mstar, lsum;
    {
      f32x4 h0v = ((const f32x4*)hcur)[lane];
      f32x4 h1v = ((const f32x4*)hcur)[64 + lane];
      float p[16];
      #pragma unroll
      for (int i = 0; i < 16; ++i)
        p[i] = ga[i].x * h0v.x + ga[i].y * h0v.y + ga[i].z * h0v.z + ga[i].w * h0v.w
             + gb[i].x * h1v.x + gb[i].y * h1v.y + gb[i].z * h1v.z + gb[i].w * h1v.w;
      #pragma unroll
      for (int off = 32; off > 0; off >>= 1) {
        #pragma unroll
        for (int i = 0; i < 16; ++i) p[i] += __shfl_xor(p[i], off);
      }
      float m = p[0];
      #pragma unroll
      for (int i = 1; i < 16; ++i) m = fmaxf(m, p[i]);
      float l = 0.f;
      f32x4 c0 = {0.f,0.f,0.f,0.f}, c1 = {0.f,0.f,0.f,0.f};
      #pragma unroll
      for (int i = 0; i < 16; ++i) {
        float e = __expf(p[i] - m);
        l += e;
        c0 += e * ga[i];
        c1 += e * gb[i];
      }
      float* ctx_lds = smem + L_MRG;
      float* ml_lds  = smem + L_ML;
      *(f32x4*)(ctx_lds + wv * 512 + lane * 4)       = c0;
      *(f32x4*)(ctx_lds + wv * 512 + 256 + lane * 4) = c1;
      if (lane == 0) { ml_lds[wv * 2] = m; ml_lds[wv * 2 + 1] = l; }
      __syncthreads();
      mstar = ml_lds[0];
      #pragma unroll
      for (int w = 1; w < 8; ++w) mstar = fmaxf(mstar, ml_lds[w * 2]);
      lsum = 0.f;
      float csum = 0.f;
      #pragma unroll
      for (int w = 0; w < 8; ++w) {
        float sc = __expf(ml_lds[w * 2] - mstar);
        lsum += sc * ml_lds[w * 2 + 1];
        csum += sc * ctx_lds[w * 512 + tid];
      }
      smem[L_CTX + tid] = csum;     // own partial kept local
      st_g1(blk_own + tid, csum);
      if (tid == 0) st_g2(blk_own + 512, f32x2{mstar, lsum});
      vm_drain();
      __syncthreads();
      if (tid == 0) st_gu(ac_own, (unsigned)(u + 1));
    }

    // ---- 3c: merge partials -> ctx; h-update GEMV ----
    {
      if (wv == 0) poll3_ge(ac1, ac2, ac3, (unsigned)(u + 1));
      __syncthreads();
      float v1, v2, v3; f32x2 mlA, mlB, mlC;
      ld_3c(blk1 + tid, blk2 + tid, blk3 + tid,
            blk1 + 512, blk2 + 512, blk3 + 512, v1, v2, v3, mlA, mlB, mlC);
      float mb = fmaxf(fmaxf(mstar, mlA.x), fmaxf(mlB.x, mlC.x));
      float s0 = __expf(mstar - mb), s1 = __expf(mlA.x - mb);
      float s2 = __expf(mlB.x - mb), s3 = __expf(mlC.x - mb);
      float inv = 1.0f / (s0 * lsum + s1 * mlA.y + s2 * mlB.y + s3 * mlC.y);
      float cval = (s0 * smem[L_CTX + tid] + s1 * v1 + s2 * v2 + s3 * v3) * inv;
      __syncthreads();              // L_CTX reads done before overwrite
      smem[L_CTX + tid] = cval;
      __syncthreads();
      const f32x4* ctx4 = (const f32x4*)(smem + L_CTX);
      float acc = zacc;
      #pragma unroll
      for (int i = 0; i < 20; ++i) {
        f32x4 cv = ctx4[4 * i + kq];
        acc += wihh[i].x * cv.x + wihh[i].y * cv.y + wihh[i].z * cv.z + wihh[i].w * cv.w;
      }
      const f32x4* tl = (const f32x4*)(smem + L_TAIL + (tid >> 2) * 204);
      #pragma unroll
      for (int t = 0; t < 12; ++t) {
        f32x4 wv4 = tl[4 * t + kq];
        f32x4 cv = ctx4[80 + 4 * t + kq];
        acc += wv4.x * cv.x + wv4.y * cv.y + wv4.z * cv.z + wv4.w * cv.w;
      }
      acc += __shfl_xor(acc, 1);
      acc += __shfl_xor(acc, 2);
      float hnew = tanhf(acc + bp3);
      if (kq == 0) st_g1(h3xg + (size_t)b * 512 + part * 128 + (tid >> 2), hnew);
      vm_drain();
      __syncthreads();
      if (tid == 0) st_gu(hc_own, (unsigned)(513 + u));
      if (wv == 0) poll3_ge(hc1, hc2, hc3, (unsigned)(513 + u));
      __syncthreads();
      if (tid < 128) {
        f32x4 hv = ld_g4(h3xg + (size_t)b * 512 + (size_t)tid * 4);
        ((f32x4*)hoth)[tid] = hv;
      }
      __syncthreads();
    }

    // ---- fixed-point early exit: h_{u+1} == h_u bitwise => all later equal
    {
      bool eq = (hoth[tid] == hcur[tid]);
      unsigned long long bal = __ballot(eq);
      if (lane == 0) smem[L_FLG + wv] = (bal == ~0ull) ? 1.f : 0.f;
      __syncthreads();
      float allf = 1.f;
      #pragma unroll
      for (int w = 0; w < 8; ++w) allf = fminf(allf, smem[L_FLG + w]);
      float* t = hcur; hcur = hoth; hoth = t;
      __syncthreads();
      if (allf != 0.f) break;
    }
  }

  // ================= final: out = h_post @ W_fc^T + b_fc =====================
  if (part == 0) {
    float pv = hcur[tid] * Wfc[tid];
    #pragma unroll
    for (int off = 32; off > 0; off >>= 1) pv += __shfl_xor(pv, off);
    __syncthreads();
    if (lane == 0) smem[L_ML + wv] = pv;
    __syncthreads();
    if (tid == 0) {
      float s = 0.f;
      #pragma unroll
      for (int w = 0; w < 8; ++w) s += smem[L_ML + w];
      out[b] = s + bfc[0];
    }
  }
}

extern "C" void kernel_launch(void* const* d_in, const int* in_sizes, int n_in,
                              void* d_out, int out_size, void* d_ws, size_t ws_size,
                              hipStream_t stream) {
  (void)in_sizes; (void)n_in; (void)out_size; (void)ws_size;
  const float* inputs   = (const float*)d_in[0];
  const float* Wih_pre  = (const float*)d_in[1];
  const float* Whh_pre  = (const float*)d_in[2];
  const float* bih_pre  = (const float*)d_in[3];
  const float* bhh_pre  = (const float*)d_in[4];
  const float* Wih_post = (const float*)d_in[5];
  const float* Whh_post = (const float*)d_in[6];
  const float* bih_post = (const float*)d_in[7];
  const float* bhh_post = (const float*)d_in[8];
  const float* Wfc      = (const float*)d_in[9];
  const float* bfc      = (const float*)d_in[10];
  float* out = (float*)d_out;
  float* ws  = (float*)d_ws;

  // Zero counters + global barrier flags every launch (graph-replay safe).
  hipMemsetAsync((char*)d_ws + OFF_ACTR * sizeof(float), 0,
                 (OFF_END - OFF_ACTR) * sizeof(float), stream);

  attn_fused<<<dim3(NWG), dim3(NTHR), 0, stream>>>(
      inputs, Wih_pre, Whh_pre, bih_pre, bhh_pre,
      Wih_post, Whh_post, bih_post, bhh_post, Wfc, bfc, out, ws);
}

// Round 7
// 13493.167 us; speedup vs baseline: 1.4747x; 1.4747x over previous
//
#include <hip/hip_runtime.h>
#include <math.h>

#define NWG 256
#define NTHR 512
static constexpr int S = 512, B = 64, I = 128, H = 512;

// ws layout (float units)
static constexpr size_t OFF_BUF0   = 0;                                  // S*B*H: x_proj -> out_pre in place
static constexpr size_t OFF_PCTX   = (size_t)S * B * H;                  // [64][4][520] pctx blocks (P2 h-exch unions here)
static constexpr size_t OFF_H3X    = OFF_PCTX + (size_t)64 * 4 * 520;    // [64][512] P3 h pieces
static constexpr size_t OFF_ACTR   = OFF_H3X + (size_t)64 * 512;         // [64][4][16] u32 pctx counters
static constexpr size_t OFF_HCTR   = OFF_ACTR + (size_t)64 * 4 * 16;     // [64][4][16] u32 h counters
static constexpr size_t OFF_GFLAGS = OFF_HCTR + (size_t)64 * 4 * 16;     // [256][16] u32 global barrier flags
static constexpr size_t OFF_END    = OFF_GFLAGS + (size_t)256 * 16;

typedef float f32x2 __attribute__((ext_vector_type(2)));
typedef float f32x4 __attribute__((ext_vector_type(4)));
#define PIN4(x) asm volatile("" : "+v"(x))

// ---- coherent (sc0 sc1: L1+L2 bypass, served at L3 coherence point) ops ----
__device__ __forceinline__ void st_g1(float* p, float v) {
  asm volatile("global_store_dword %0, %1, off sc0 sc1" :: "v"(p), "v"(v) : "memory");
}
__device__ __forceinline__ void st_g2(float* p, f32x2 v) {
  asm volatile("global_store_dwordx2 %0, %1, off sc0 sc1" :: "v"(p), "v"(v) : "memory");
}
__device__ __forceinline__ void st_gu(unsigned* p, unsigned v) {
  asm volatile("global_store_dword %0, %1, off sc0 sc1" :: "v"(p), "v"(v) : "memory");
}
__device__ __forceinline__ f32x4 ld_g4(const float* p) {
  f32x4 v;
  asm volatile("global_load_dwordx4 %0, %1, off sc0 sc1\n\ts_waitcnt vmcnt(0)"
               : "=&v"(v) : "v"(p) : "memory");
  return v;
}
__device__ __forceinline__ void ld_3c(const float* v0, const float* v1, const float* v2,
                                      const float* m0, const float* m1, const float* m2,
                                      float& a, float& b, float& c,
                                      f32x2& x, f32x2& y, f32x2& z) {
  asm volatile("global_load_dword %0, %6, off sc0 sc1\n\t"
               "global_load_dword %1, %7, off sc0 sc1\n\t"
               "global_load_dword %2, %8, off sc0 sc1\n\t"
               "global_load_dwordx2 %3, %9, off sc0 sc1\n\t"
               "global_load_dwordx2 %4, %10, off sc0 sc1\n\t"
               "global_load_dwordx2 %5, %11, off sc0 sc1\n\t"
               "s_waitcnt vmcnt(0)"
               : "=&v"(a), "=&v"(b), "=&v"(c), "=&v"(x), "=&v"(y), "=&v"(z)
               : "v"(v0), "v"(v1), "v"(v2), "v"(m0), "v"(m1), "v"(m2) : "memory");
}
__device__ __forceinline__ void poll3_ge(const unsigned* p0, const unsigned* p1,
                                         const unsigned* p2, unsigned tgt) {
  unsigned a, b, c;
  do {
    asm volatile("global_load_dword %0, %3, off sc0 sc1\n\t"
                 "global_load_dword %1, %4, off sc0 sc1\n\t"
                 "global_load_dword %2, %5, off sc0 sc1\n\t"
                 "s_waitcnt vmcnt(0)"
                 : "=&v"(a), "=&v"(b), "=&v"(c)
                 : "v"(p0), "v"(p1), "v"(p2) : "memory");
  } while (a < tgt || b < tgt || c < tgt);
}
__device__ __forceinline__ void vm_drain() { asm volatile("s_waitcnt vmcnt(0)" ::: "memory"); }

__device__ __forceinline__ void gbar_all(unsigned* gflags, int wg, unsigned gen) {
  __syncthreads();
  if (threadIdx.x == 0)
    __hip_atomic_store(gflags + (size_t)wg * 16, gen, __ATOMIC_RELEASE, __HIP_MEMORY_SCOPE_AGENT);
  if (threadIdx.x < 256) {
    while (__hip_atomic_load(gflags + (size_t)threadIdx.x * 16, __ATOMIC_ACQUIRE,
                             __HIP_MEMORY_SCOPE_AGENT) < gen) {}
  }
  __syncthreads();
}

// LDS arena (floats). P1 uses [0,8192) as tile; P2/P3 overlay:
static constexpr int L_MRG = 0;      // 8x512 merge
static constexpr int L_ML  = 4096;   // 16
static constexpr int L_H   = 4112;   // 512 current h
static constexpr int L_CTX = 4624;   // 512
// arena = 8192 floats (32 KB)

__global__ __launch_bounds__(NTHR) __attribute__((amdgpu_waves_per_eu(1, 2)))
void attn_fused(
    const float* __restrict__ inputs,
    const float* __restrict__ Wih_pre, const float* __restrict__ Whh_pre,
    const float* __restrict__ bih_pre, const float* __restrict__ bhh_pre,
    const float* __restrict__ Wih_post, const float* __restrict__ Whh_post,
    const float* __restrict__ bih_post, const float* __restrict__ bhh_post,
    const float* __restrict__ Wfc, const float* __restrict__ bfc,
    float* __restrict__ out, float* __restrict__ ws)
{
  float* buf0  = ws + OFF_BUF0;
  float* pctxg = ws + OFF_PCTX;
  float* h3xg  = ws + OFF_H3X;
  unsigned* actrg  = (unsigned*)(ws + OFF_ACTR);
  unsigned* hctrg  = (unsigned*)(ws + OFF_HCTR);
  unsigned* gflags = (unsigned*)(ws + OFF_GFLAGS);

  const int wg   = blockIdx.x;
  const int tid  = threadIdx.x;
  const int lane = tid & 63;
  const int wv   = tid >> 6;
  const int b    = wg & 63;
  const int part = wg >> 6;
  const int q1 = (part + 1) & 3, q2 = (part + 2) & 3, q3 = (part + 3) & 3;

  unsigned* hc_own = hctrg + ((size_t)b * 4 + part) * 16;
  unsigned* hc1 = hctrg + ((size_t)b * 4 + q1) * 16;
  unsigned* hc2 = hctrg + ((size_t)b * 4 + q2) * 16;
  unsigned* hc3 = hctrg + ((size_t)b * 4 + q3) * 16;
  unsigned* ac_own = actrg + ((size_t)b * 4 + part) * 16;
  unsigned* ac1 = actrg + ((size_t)b * 4 + q1) * 16;
  unsigned* ac2 = actrg + ((size_t)b * 4 + q2) * 16;
  unsigned* ac3 = actrg + ((size_t)b * 4 + q3) * 16;

  __shared__ __align__(16) float smem[8192];

  // ================= P1: x_proj = inputs @ W_ih_pre^T + (b_ih+b_hh) ==========
  {
    const int h = tid;
    f32x4 Wr[32];
    const f32x4* wrow = (const f32x4*)(Wih_pre + (size_t)h * I);
    #pragma unroll
    for (int c = 0; c < 32; ++c) Wr[c] = wrow[c];
    const float bias = bih_pre[h] + bhh_pre[h];
    const int r0 = wg * 128;
    for (int t2 = 0; t2 < 2; ++t2) {
      __syncthreads();
      const f32x4* src = (const f32x4*)(inputs + (size_t)(r0 + t2 * 64) * I);
      for (int idx = tid; idx < 64 * I / 4; idx += NTHR)
        ((f32x4*)smem)[idx] = src[idx];
      __syncthreads();
      for (int r = 0; r < 64; ++r) {
        const f32x4* arow = (const f32x4*)(smem + r * I);
        float acc0 = 0.f, acc1 = 0.f;
        #pragma unroll
        for (int c = 0; c < 32; c += 2) {
          f32x4 a0 = arow[c], a1 = arow[c + 1];
          acc0 += a0.x * Wr[c].x + a0.y * Wr[c].y + a0.z * Wr[c].z + a0.w * Wr[c].w;
          acc1 += a1.x * Wr[c+1].x + a1.y * Wr[c+1].y + a1.z * Wr[c+1].z + a1.w * Wr[c+1].w;
        }
        buf0[(size_t)(r0 + t2 * 64 + r) * H + h] = acc0 + acc1 + bias;
      }
    }
  }
  gbar_all(gflags, wg, 1u);

  // ================= P2: pre-RNN, 512 steps, per-batch (4 WGs) ==============
  const int j  = part * 128 + (tid >> 2);
  const int kq = tid & 3;
  {
    f32x4 wpre[32];   // only big array live in P2: fits comfortably
    const f32x4* wrow = (const f32x4*)(Whh_pre + (size_t)j * H);
    #pragma unroll
    for (int i = 0; i < 32; ++i) { wpre[i] = wrow[4 * i + kq]; PIN4(wpre[i]); }

    float* hst = smem + L_H;
    hst[tid] = 0.f;
    __syncthreads();

    for (int t = 0; t < S; ++t) {
      float* brow = buf0 + ((size_t)t * B + b) * H;
      float xp = brow[j];
      const f32x4* hst4 = (const f32x4*)hst;
      float d = 0.f;
      #pragma unroll
      for (int i = 0; i < 32; ++i) {
        f32x4 hv = hst4[4 * i + kq];     // 4 addrs, broadcast: conflict-free
        d += wpre[i].x * hv.x + wpre[i].y * hv.y + wpre[i].z * hv.z + wpre[i].w * hv.w;
      }
      d += __shfl_xor(d, 1);
      d += __shfl_xor(d, 2);
      float hnew = tanhf(xp + d);
      const int par = (t + 1) & 1;
      float* slot = pctxg + (((size_t)b * 2 + par) * 4 + part) * 128;
      if (kq == 0) {
        brow[j] = hnew;                  // out_pre in place (read after gbar)
        st_g1(slot + (tid >> 2), hnew);  // coherent exchange copy
      }
      vm_drain();
      __syncthreads();
      if (tid == 0) st_gu(hc_own, (unsigned)(t + 1));
      if (wv == 0) poll3_ge(hc1, hc2, hc3, (unsigned)(t + 1));
      __syncthreads();
      if (tid < 128) {
        f32x4 hv = ld_g4(pctxg + (((size_t)b * 2 + par) * 4) * 128 + (size_t)tid * 4);
        ((f32x4*)hst)[tid] = hv;
      }
      __syncthreads();
    }
  }
  gbar_all(gflags, wg, 2u);

  // ---- G strip register-resident: the ONLY persistent big array (128 regs) --
  f32x4 ga[16], gb[16];
  {
    const int s0 = part * 128 + wv * 16;
    #pragma unroll
    for (int i = 0; i < 16; ++i) {
      const float* row = buf0 + ((size_t)(s0 + i) * B + b) * H;
      ga[i] = *(const f32x4*)(row + lane * 4);
      gb[i] = *(const f32x4*)(row + 256 + lane * 4);
    }
  }

  // W_post rows streamed from L2 every step (2 MB/XCD, L2-resident)
  const f32x4* wihr = (const f32x4*)(Wih_post + (size_t)j * H);
  const f32x4* whhr = (const f32x4*)(Whh_post + (size_t)j * H);
  const float bp3 = bih_post[j] + bhh_post[j];

  float* blk_own = pctxg + ((size_t)b * 4 + part) * 520;
  float* blk1 = pctxg + ((size_t)b * 4 + q1) * 520;
  float* blk2 = pctxg + ((size_t)b * 4 + q2) * 520;
  float* blk3 = pctxg + ((size_t)b * 4 + q3) * 520;

  smem[L_H + tid] = 0.f;   // attention h_0 = 0
  __syncthreads();

  // ================= P3: attention loop, 512 steps, per-batch ================
  for (int u = 0; u < H; ++u) {
    // ---- 3a: scores + softmax partials + ctx partial (registers) ----
    float mstar, lsum;
    {
      f32x4 h0v = ((const f32x4*)(smem + L_H))[lane];
      f32x4 h1v = ((const f32x4*)(smem + L_H))[64 + lane];
      float p[16];
      #pragma unroll
      for (int i = 0; i < 16; ++i)
        p[i] = ga[i].x * h0v.x + ga[i].y * h0v.y + ga[i].z * h0v.z + ga[i].w * h0v.w
             + gb[i].x * h1v.x + gb[i].y * h1v.y + gb[i].z * h1v.z + gb[i].w * h1v.w;
      #pragma unroll
      for (int off = 32; off > 0; off >>= 1) {
        #pragma unroll
        for (int i = 0; i < 16; ++i) p[i] += __shfl_xor(p[i], off);
      }
      float m = p[0];
      #pragma unroll
      for (int i = 1; i < 16; ++i) m = fmaxf(m, p[i]);
      float l = 0.f;
      f32x4 c0 = {0.f,0.f,0.f,0.f}, c1 = {0.f,0.f,0.f,0.f};
      #pragma unroll
      for (int i = 0; i < 16; ++i) {
        float e = __expf(p[i] - m);
        l += e;
        c0 += e * ga[i];
        c1 += e * gb[i];
      }
      float* ctx_lds = smem + L_MRG;
      float* ml_lds  = smem + L_ML;
      *(f32x4*)(ctx_lds + wv * 512 + lane * 4)       = c0;
      *(f32x4*)(ctx_lds + wv * 512 + 256 + lane * 4) = c1;
      if (lane == 0) { ml_lds[wv * 2] = m; ml_lds[wv * 2 + 1] = l; }
      __syncthreads();
      mstar = ml_lds[0];
      #pragma unroll
      for (int w = 1; w < 8; ++w) mstar = fmaxf(mstar, ml_lds[w * 2]);
      lsum = 0.f;
      float csum = 0.f;
      #pragma unroll
      for (int w = 0; w < 8; ++w) {
        float sc = __expf(ml_lds[w * 2] - mstar);
        lsum += sc * ml_lds[w * 2 + 1];
        csum += sc * ctx_lds[w * 512 + tid];
      }
      smem[L_CTX + tid] = csum;          // own partial stays local
      st_g1(blk_own + tid, csum);        // publish payload
      if (tid == 0) st_g2(blk_own + 512, f32x2{mstar, lsum});
      vm_drain();
      __syncthreads();
      if (tid == 0) st_gu(ac_own, (unsigned)(u + 1));
    }

    // ---- z2 = Whh_post(row j) . h  : streamed from L2 WHILE peers finish 3a
    float zacc = 0.f;
    {
      const f32x4* h4 = (const f32x4*)(smem + L_H);
      #pragma unroll
      for (int i = 0; i < 32; ++i) {
        f32x4 w = whhr[4 * i + kq];
        f32x4 hv = h4[4 * i + kq];
        zacc += w.x * hv.x + w.y * hv.y + w.z * hv.z + w.w * hv.w;
      }
    }

    // ---- 3c: merge partials -> ctx; wih GEMV streamed; h-update ----
    {
      if (wv == 0) poll3_ge(ac1, ac2, ac3, (unsigned)(u + 1));
      __syncthreads();
      float v1, v2, v3; f32x2 mlA, mlB, mlC;
      ld_3c(blk1 + tid, blk2 + tid, blk3 + tid,
            blk1 + 512, blk2 + 512, blk3 + 512, v1, v2, v3, mlA, mlB, mlC);
      float mb = fmaxf(fmaxf(mstar, mlA.x), fmaxf(mlB.x, mlC.x));
      float s0 = __expf(mstar - mb), s1 = __expf(mlA.x - mb);
      float s2 = __expf(mlB.x - mb), s3 = __expf(mlC.x - mb);
      float inv = 1.0f / (s0 * lsum + s1 * mlA.y + s2 * mlB.y + s3 * mlC.y);
      float cval = (s0 * smem[L_CTX + tid] + s1 * v1 + s2 * v2 + s3 * v3) * inv;
      __syncthreads();                   // L_CTX reads done before overwrite
      smem[L_CTX + tid] = cval;
      __syncthreads();
      const f32x4* ctx4 = (const f32x4*)(smem + L_CTX);
      float acc = zacc;
      #pragma unroll
      for (int i = 0; i < 32; ++i) {
        f32x4 w = wihr[4 * i + kq];      // streamed from L2
        f32x4 cv = ctx4[4 * i + kq];     // broadcast, conflict-free
        acc += w.x * cv.x + w.y * cv.y + w.z * cv.z + w.w * cv.w;
      }
      acc += __shfl_xor(acc, 1);
      acc += __shfl_xor(acc, 2);
      float hnew = tanhf(acc + bp3);
      if (kq == 0) st_g1(h3xg + (size_t)b * 512 + part * 128 + (tid >> 2), hnew);
      vm_drain();
      __syncthreads();
      if (tid == 0) st_gu(hc_own, (unsigned)(513 + u));
      if (wv == 0) poll3_ge(hc1, hc2, hc3, (unsigned)(513 + u));
      __syncthreads();
      if (tid < 128) {
        f32x4 hv = ld_g4(h3xg + (size_t)b * 512 + (size_t)tid * 4);
        ((f32x4*)(smem + L_H))[tid] = hv;
      }
      __syncthreads();
    }
  }

  // ================= final: out = h_post @ W_fc^T + b_fc =====================
  if (part == 0) {
    float pv = smem[L_H + tid] * Wfc[tid];
    #pragma unroll
    for (int off = 32; off > 0; off >>= 1) pv += __shfl_xor(pv, off);
    __syncthreads();
    if (lane == 0) smem[L_ML + wv] = pv;
    __syncthreads();
    if (tid == 0) {
      float s = 0.f;
      #pragma unroll
      for (int w = 0; w < 8; ++w) s += smem[L_ML + w];
      out[b] = s + bfc[0];
    }
  }
}

extern "C" void kernel_launch(void* const* d_in, const int* in_sizes, int n_in,
                              void* d_out, int out_size, void* d_ws, size_t ws_size,
                              hipStream_t stream) {
  (void)in_sizes; (void)n_in; (void)out_size; (void)ws_size;
  const float* inputs   = (const float*)d_in[0];
  const float* Wih_pre  = (const float*)d_in[1];
  const float* Whh_pre  = (const float*)d_in[2];
  const float* bih_pre  = (const float*)d_in[3];
  const float* bhh_pre  = (const float*)d_in[4];
  const float* Wih_post = (const float*)d_in[5];
  const float* Whh_post = (const float*)d_in[6];
  const float* bih_post = (const float*)d_in[7];
  const float* bhh_post = (const float*)d_in[8];
  const float* Wfc      = (const float*)d_in[9];
  const float* bfc      = (const float*)d_in[10];
  float* out = (float*)d_out;
  float* ws  = (float*)d_ws;

  // Zero counters + global barrier flags every launch (graph-replay safe).
  hipMemsetAsync((char*)d_ws + OFF_ACTR * sizeof(float), 0,
                 (OFF_END - OFF_ACTR) * sizeof(float), stream);

  attn_fused<<<dim3(NWG), dim3(NTHR), 0, stream>>>(
      inputs, Wih_pre, Whh_pre, bih_pre, bhh_pre,
      Wih_post, Whh_post, bih_post, bhh_post, Wfc, bfc, out, ws);
}